// Round 7
// baseline (346.732 us; speedup 1.0000x reference)
//
#include <hip/hip_runtime.h>

// N=4096 nodes, H=8 heads, D=64, C=512. All fp32 in, fp32 out.
// Pipeline: convert(+stat zero) -> GEMM(qkv+skip, Q pre-scaled by 0.125*log2e,
// V also written transposed) -> split-j(3) max-free flash attn (128 i-rows,
// 8 waves, exp2 path, bf16 partials) -> combine(+skip+stats) -> GraphNorm+L2.

typedef short s8v __attribute__((ext_vector_type(8)));       // 8 bf16 (A/B frag)
typedef unsigned short u16x8 __attribute__((ext_vector_type(8)));
typedef unsigned short u16x4 __attribute__((ext_vector_type(4)));
typedef float f4 __attribute__((ext_vector_type(4)));        // C/D frag
typedef unsigned short u16;

__device__ __forceinline__ u16 f2bf(float f) {               // RNE
    union { float f; unsigned u; } v; v.f = f;
    unsigned r = v.u + 0x7fffu + ((v.u >> 16) & 1u);
    return (u16)(r >> 16);
}
__device__ __forceinline__ u16 f2bf_hu(float f) {            // round-half-up, 2 ops (P>=0)
    union { float f; unsigned u; } v; v.f = f;
    return (u16)((v.u + 0x8000u) >> 16);
}
__device__ __forceinline__ float bf2f(u16 h) {
    union { unsigned u; float f; } v; v.u = ((unsigned)h) << 16;
    return v.f;
}

#define GLD16(g, l) __builtin_amdgcn_global_load_lds( \
    (const __attribute__((address_space(1))) void*)(g), \
    (__attribute__((address_space(3))) void*)(l), 16, 0, 0)

// ---------- x fp32 -> bf16 ; block 0 also zeroes the stats accumulator ----------
__global__ __launch_bounds__(256) void k_convx(const float* __restrict__ x,
                                               u16* __restrict__ xb,
                                               float* __restrict__ stats) {
    if (blockIdx.x == 0) {
        int t = threadIdx.x;
        stats[t] = 0.f; stats[256 + t] = 0.f; stats[512 + t] = 0.f; stats[768 + t] = 0.f;
    }
    size_t i = ((size_t)blockIdx.x * 256 + threadIdx.x) * 8;
    float4 a = *(const float4*)(x + i);
    float4 b = *(const float4*)(x + i + 4);
    u16x8 o;
    o[0]=f2bf(a.x); o[1]=f2bf(a.y); o[2]=f2bf(a.z); o[3]=f2bf(a.w);
    o[4]=f2bf(b.x); o[5]=f2bf(b.y); o[6]=f2bf(b.z); o[7]=f2bf(b.w);
    *(u16x8*)(xb + i) = o;
}

// ---------- W concat transpose+convert: wb[n][k] = W_seg[k][n&511], bf16 ----------
__global__ __launch_bounds__(256) void k_transw(const float* __restrict__ Wq,
                                                const float* __restrict__ Wk,
                                                const float* __restrict__ Wv,
                                                const float* __restrict__ Ws,
                                                u16* __restrict__ wb) {
    __shared__ float tile[64][65];
    int k0 = blockIdx.x * 64;
    int n0 = blockIdx.y * 64;
    const float* W = (n0 < 512) ? Wq : (n0 < 1024) ? Wk : (n0 < 1536) ? Wv : Ws;
    int col0 = n0 & 511;
    int t = threadIdx.x;
#pragma unroll
    for (int q = 0; q < 4; q++) {
        int idx = t + 256 * q;
        int row = idx >> 4, c4 = (idx & 15) * 4;
        float4 v = *(const float4*)&W[(size_t)(k0 + row) * 512 + col0 + c4];
        tile[row][c4 + 0] = v.x; tile[row][c4 + 1] = v.y;
        tile[row][c4 + 2] = v.z; tile[row][c4 + 3] = v.w;
    }
    __syncthreads();
#pragma unroll
    for (int q = 0; q < 2; q++) {
        int idx = t + 256 * q;
        int row = idx >> 3, c8 = (idx & 7) * 8;
        u16x8 o;
#pragma unroll
        for (int j = 0; j < 8; j++) o[j] = f2bf(tile[c8 + j][row]);
        *(u16x8*)&wb[(size_t)(n0 + row) * 4096 + k0 + c8] = o;
    }
}

// ---------- GEMM: qkvs[m][n] = bf16( (sum_k xb[m][k]*wb[n][k] + bias[n]) * scale_seg )
// 128x128 tile, BK=64, XOR-swizzled rows (0 conflicts, verified R5), 8 waves
// (16 waves/CU, verified R6). Q pre-scaled by 0.125*log2e; V also -> vt[d][m].
__global__ __launch_bounds__(512) void k_gemm(const u16* __restrict__ xb,
                                              const u16* __restrict__ wb,
                                              const float* __restrict__ bq,
                                              const float* __restrict__ bk,
                                              const float* __restrict__ bv,
                                              const float* __restrict__ bs,
                                              u16* __restrict__ qkvs,
                                              u16* __restrict__ vt) {
    __shared__ __align__(16) u16 A_lds[128 * 64];
    __shared__ __align__(16) u16 B_lds[128 * 64];
    int tid = threadIdx.x;
    int w = tid >> 6, lane = tid & 63;
    int wr = w >> 1, wc = w & 1;
    int L = lane & 15, q = lane >> 4;
    int m0 = blockIdx.y * 128, n0 = blockIdx.x * 128;

    const f4 fz = {0.f, 0.f, 0.f, 0.f};
    f4 acc[2][4];
#pragma unroll
    for (int r = 0; r < 2; r++)
#pragma unroll
        for (int t = 0; t < 4; t++) acc[r][t] = fz;

    int r8 = lane >> 3;                 // source row within 8-row group
    int csw = ((lane & 7) ^ r8) * 8;    // XOR-swizzled source chunk (u16 units)
    const u16* gS;
    u16* lds_s;
    int rb0;
    if (w < 4) { gS = xb + (size_t)(m0 + r8) * 4096 + csw; lds_s = A_lds; rb0 = 32 * w; }
    else       { gS = wb + (size_t)(n0 + r8) * 4096 + csw; lds_s = B_lds; rb0 = 32 * (w - 4); }

    for (int kt = 0; kt < 64; ++kt) {
        int k0 = kt * 64;
#pragma unroll
        for (int g = 0; g < 4; g++) {
            int rb = rb0 + 8 * g;
            GLD16(gS + (size_t)rb * 4096 + k0, &lds_s[rb * 64]);
        }
        __syncthreads();
        s8v a[2][2], b[4][2];
#pragma unroll
        for (int r = 0; r < 2; r++) {
            int row = wr * 32 + 16 * r + L;
            int r7 = row & 7;
            a[r][0] = *(const s8v*)&A_lds[row * 64 + ((q ^ r7) * 8)];
            a[r][1] = *(const s8v*)&A_lds[row * 64 + (((4 + q) ^ r7) * 8)];
        }
#pragma unroll
        for (int t = 0; t < 4; t++) {
            int row = wc * 64 + 16 * t + L;
            int r7 = row & 7;
            b[t][0] = *(const s8v*)&B_lds[row * 64 + ((q ^ r7) * 8)];
            b[t][1] = *(const s8v*)&B_lds[row * 64 + (((4 + q) ^ r7) * 8)];
        }
#pragma unroll
        for (int r = 0; r < 2; r++)
#pragma unroll
            for (int t = 0; t < 4; t++) {
                acc[r][t] = __builtin_amdgcn_mfma_f32_16x16x32_bf16(a[r][0], b[t][0], acc[r][t], 0, 0, 0);
                acc[r][t] = __builtin_amdgcn_mfma_f32_16x16x32_bf16(a[r][1], b[t][1], acc[r][t], 0, 0, 0);
            }
        __syncthreads();
    }

#pragma unroll
    for (int t = 0; t < 4; t++) {
        int n = n0 + wc * 64 + 16 * t + L;
        int seg = n >> 9, o = n & 511;
        const float* bp = (seg == 0) ? bq : (seg == 1) ? bk : (seg == 2) ? bv : bs;
        float bias = bp[o];
        float scale = (seg == 0) ? 0.1803368801f : 1.f;  // 0.125 * log2(e)
#pragma unroll
        for (int r = 0; r < 2; r++) {
            int mbase = m0 + wr * 32 + 16 * r + 4 * q;
            u16x4 hv;
#pragma unroll
            for (int q2 = 0; q2 < 4; q2++) {
                u16 hb = f2bf((acc[r][t][q2] + bias) * scale);
                hv[q2] = hb;
                qkvs[(size_t)(mbase + q2) * 2048 + n] = hb;
            }
            if (seg == 2)  // fused V transpose: vt[d][m], 4 contiguous m -> 8B store
                *(u16x4*)&vt[(size_t)(n - 1024) * 4096 + mbase] = hv;
        }
    }
}

// ---------- split-j(3) max-free attention, 128 i-rows x 8 waves per block ----------
// block = (i-tile 128, head h, split sp in {0,1,2} -> {22,21,21} j-tiles of 64).
// Wave w owns i-rows 16w..16w+15. K/V'/Q staged via GLD16 into unpadded
// stride-64 tiles with XOR chunk swizzle (conflict-free b128 reads, verified).
// p = exp2(min(qk' + xx*qe', 115)); partials o (bf16), l, sa are pure sums.
__global__ __launch_bounds__(512, 6) void k_attn(const u16* __restrict__ qkvs,
                                                 const u16* __restrict__ xb,
                                                 const u16* __restrict__ vt,
                                                 const float* __restrict__ we,
                                                 u16* __restrict__ o_part,
                                                 float* __restrict__ lsa_part) {
    __shared__ __align__(16) u16 K_lds[64 * 64];    // swizzled [j][d]
    __shared__ __align__(16) u16 V_lds[64 * 64];    // swizzled [d][j]
    __shared__ __align__(16) u16 P_lds[128 * 72];   // padded (also Q staging, stride 64)
    __shared__ __align__(16) u16 X_lds[64 * 136];   // padded bf16 x tile [j][i]
    __shared__ float qe_s[128];

    int tid = threadIdx.x;
    int w = tid >> 6, lane = tid & 63;
    int L = lane & 15, q = lane >> 4;
    int i0 = blockIdx.x * 128;
    int h = blockIdx.y, hc = h * 64;
    int sp = blockIdx.z;
    int t0 = (sp == 0) ? 0 : (1 + 21 * sp);   // {0, 22, 43}
    int tn = sp ? 21 : 22;

    int r8 = lane >> 3;                 // GLD16 source row within 8-row group
    int csw = ((lane & 7) ^ r8) * 8;    // XOR-swizzled source chunk (u16 units)

    // ---- stage Q (128 rows) into P_lds (stride 64, swizzled) ----
    {
        const u16* g0 = qkvs + (size_t)i0 * 2048 + hc;
#pragma unroll
        for (int ih = 0; ih < 2; ih++) {
            int rb = 16 * w + 8 * ih;
            GLD16(g0 + (size_t)(rb + r8) * 2048 + csw, &P_lds[rb * 64]);
        }
    }
    __syncthreads();

    s8v qf[2];
#pragma unroll
    for (int c = 0; c < 2; c++) {
        int row = 16 * w + L;
        qf[c] = *(const s8v*)&P_lds[row * 64 + (((4 * c + q) ^ (row & 7)) * 8)];
    }
    if (tid < 128) {  // qe[i] = q'_i . we_h  (q' already carries 0.125*log2e)
        float s = 0.f;
        int r7 = tid & 7;
#pragma unroll
        for (int d = 0; d < 64; d++)
            s += bf2f(P_lds[tid * 64 + ((d >> 3) ^ r7) * 8 + (d & 7)]) * we[hc + d];
        qe_s[tid] = s;
    }
    __syncthreads();

    float qe_r[4];
#pragma unroll
    for (int r = 0; r < 4; r++) qe_r[r] = qe_s[16 * w + 4 * q + r];

    const f4 fz = {0.f, 0.f, 0.f, 0.f};
    f4 o_acc[4];
    float l_p[4], sa_p[4];
#pragma unroll
    for (int r = 0; r < 4; r++) { l_p[r] = 0.f; sa_p[r] = 0.f; }
#pragma unroll
    for (int t = 0; t < 4; t++) o_acc[t] = fz;

    for (int jt64 = 0; jt64 < tn; ++jt64) {
        int j0 = (t0 + jt64) * 64;
        // stage K: wave w stages rows 8w..8w+7
        GLD16(qkvs + (size_t)(j0 + 8 * w + r8) * 2048 + 512 + hc + csw, &K_lds[8 * w * 64]);
        // stage V^T: rows are d
        GLD16(vt + (size_t)(hc + 8 * w + r8) * 4096 + j0 + csw, &V_lds[8 * w * 64]);
        // stage X tile bf16: X_lds[j][i], 64 x 128, stride 136
#pragma unroll
        for (int qq = 0; qq < 2; qq++) {
            int idx = tid + 512 * qq;
            int row = idx >> 4, c8 = (idx & 15) * 8;
            *(s8v*)&X_lds[row * 136 + c8] =
                *(const s8v*)&xb[(size_t)(j0 + row) * 4096 + i0 + c8];
        }
        __syncthreads();

#pragma unroll
        for (int jt = 0; jt < 4; jt++) {
            int n = L + 16 * jt;
            int n7 = n & 7;
            s8v b0 = *(const s8v*)&K_lds[n * 64 + ((q ^ n7) * 8)];
            s8v b1 = *(const s8v*)&K_lds[n * 64 + (((4 + q) ^ n7) * 8)];
            f4 acc = fz;
            acc = __builtin_amdgcn_mfma_f32_16x16x32_bf16(qf[0], b0, acc, 0, 0, 0);
            acc = __builtin_amdgcn_mfma_f32_16x16x32_bf16(qf[1], b1, acc, 0, 0, 0);
            u16x4 xv4 = *(const u16x4*)&X_lds[n * 136 + 16 * w + 4 * q];
#pragma unroll
            for (int r = 0; r < 4; r++) {
                float xx = bf2f(xv4[r]);
                float s = fminf(acc[r] + xx * qe_r[r], 115.f);   // log2 units
                float p = __builtin_amdgcn_exp2f(s);
                l_p[r] += p;
                sa_p[r] += p * xx;
                P_lds[(16 * w + 4 * q + r) * 72 + n] = f2bf_hu(p);
            }
        }

        // PV (wave-local P round-trip; same-wave rows only)
        {
            int row = 16 * w + L;
            s8v a0 = *(const s8v*)&P_lds[row * 72 + q * 8];
            s8v a1 = *(const s8v*)&P_lds[row * 72 + 32 + q * 8];
#pragma unroll
            for (int t = 0; t < 4; t++) {
                int n = L + 16 * t;
                int n7 = n & 7;
                s8v b0 = *(const s8v*)&V_lds[n * 64 + ((q ^ n7) * 8)];
                s8v b1 = *(const s8v*)&V_lds[n * 64 + (((4 + q) ^ n7) * 8)];
                o_acc[t] = __builtin_amdgcn_mfma_f32_16x16x32_bf16(a0, b0, o_acc[t], 0, 0, 0);
                o_acc[t] = __builtin_amdgcn_mfma_f32_16x16x32_bf16(a1, b1, o_acc[t], 0, 0, 0);
            }
        }
        __syncthreads();
    }

    // epilogue: raw partials (division happens in k_comb after summing l)
#pragma unroll
    for (int r = 0; r < 4; r++) {
        float l = l_p[r], sa = sa_p[r];
        l += __shfl_xor(l, 1);  sa += __shfl_xor(sa, 1);
        l += __shfl_xor(l, 2);  sa += __shfl_xor(sa, 2);
        l += __shfl_xor(l, 4);  sa += __shfl_xor(sa, 4);
        l += __shfl_xor(l, 8);  sa += __shfl_xor(sa, 8);
        int i = i0 + 16 * w + 4 * q + r;
#pragma unroll
        for (int t = 0; t < 4; t++)
            o_part[((size_t)sp * 4096 + i) * 512 + hc + L + 16 * t] = f2bf(o_acc[t][r]);
        if (L == 0) {
            size_t bi = (((size_t)sp * 4096 + i) * 8 + h) * 2;
            lsa_part[bi] = l;
            lsa_part[bi + 1] = sa;
        }
    }
}

// ---------- combine 3 splits + skip + out_pre + column stats ----------
__global__ __launch_bounds__(512) void k_comb(const u16* __restrict__ o_part,
                                              const float* __restrict__ lsa,
                                              const u16* __restrict__ qkvs,
                                              const float* __restrict__ we,
                                              float* __restrict__ out_pre,
                                              float* __restrict__ stats) {
    int c = threadIdx.x;
    int r0 = blockIdx.x * 16;
    int h = c >> 6;
    float wec = we[c];
    float s = 0.f, s2 = 0.f;
    for (int ii = 0; ii < 16; ii++) {
        int i = r0 + ii;
        float l = 0.f, sa = 0.f, o = 0.f;
#pragma unroll
        for (int spp = 0; spp < 3; spp++) {
            size_t b = (((size_t)spp * 4096 + i) * 8 + h) * 2;
            l += lsa[b];
            sa += lsa[b + 1];
            o += bf2f(o_part[((size_t)spp * 4096 + i) * 512 + c]);
        }
        float inv = 1.f / l;
        float v = (o + sa * wec) * inv + bf2f(qkvs[(size_t)i * 2048 + 1536 + c]);
        out_pre[(size_t)i * 512 + c] = v;
        s += v; s2 += v * v;
    }
    atomicAdd(&stats[c], s);
    atomicAdd(&stats[512 + c], s2);
}

// ---------- GraphNorm + per-row L2 normalize ----------
__global__ __launch_bounds__(512) void k_final(const float* __restrict__ out_pre,
                                               const float* __restrict__ stats,
                                               const float* __restrict__ gn_w,
                                               const float* __restrict__ gn_b,
                                               const float* __restrict__ gn_ms,
                                               float* __restrict__ out) {
    __shared__ float red[8];
    int c = threadIdx.x;
    int i = blockIdx.x;
    float mean = stats[c] * (1.f / 4096.f);
    float ex2 = stats[512 + c] * (1.f / 4096.f);
    float g = gn_ms[c];
    float var = ex2 - (2.f * g - g * g) * mean * mean;
    float y = gn_w[c] * (out_pre[(size_t)i * 512 + c] - g * mean) * rsqrtf(var + 1e-5f) + gn_b[c];
    float qv = y * y;
    qv += __shfl_xor(qv, 1);  qv += __shfl_xor(qv, 2);  qv += __shfl_xor(qv, 4);
    qv += __shfl_xor(qv, 8);  qv += __shfl_xor(qv, 16); qv += __shfl_xor(qv, 32);
    if ((c & 63) == 0) red[c >> 6] = qv;
    __syncthreads();
    float tot = 0.f;
#pragma unroll
    for (int k = 0; k < 8; k++) tot += red[k];
    out[(size_t)i * 512 + c] = y * rsqrtf(tot);
}

extern "C" void kernel_launch(void* const* d_in, const int* in_sizes, int n_in,
                              void* d_out, int out_size, void* d_ws, size_t ws_size,
                              hipStream_t stream) {
    (void)in_sizes; (void)n_in; (void)out_size; (void)ws_size;
    const float* x    = (const float*)d_in[0];
    const float* Wq   = (const float*)d_in[1];
    const float* bq   = (const float*)d_in[2];
    const float* Wk   = (const float*)d_in[3];
    const float* bk   = (const float*)d_in[4];
    const float* Wv   = (const float*)d_in[5];
    const float* bv   = (const float*)d_in[6];
    const float* we   = (const float*)d_in[7];
    const float* Ws   = (const float*)d_in[8];
    const float* bs   = (const float*)d_in[9];
    const float* gnw  = (const float*)d_in[10];
    const float* gnb  = (const float*)d_in[11];
    const float* gnms = (const float*)d_in[12];
    float* out = (float*)d_out;

    char* ws = (char*)d_ws;
    // Region reuse (all launches sequential on `stream`):
    //   [0,32M):    xb (convx..attn) then out_pre overlays (comb..final)
    //   [32M,48M):  wb (transw..gemm) then o_part bf16 3x4MB overlays (attn..comb)
    //   [48M,64M):  qkvs (gemm..comb)
    //   [64M,68M):  vt (gemm..attn)
    //   [68M,..):   lsa_part (768KB) ; stats (4KB)
    u16* xb        = (u16*)(ws);
    float* out_pre = (float*)(ws);
    u16* wb        = (u16*)(ws + (size_t)33554432);
    u16* o_part    = (u16*)(ws + (size_t)33554432);
    u16* qkvs      = (u16*)(ws + (size_t)50331648);
    u16* vt        = (u16*)(ws + (size_t)67108864);
    float* lsa     = (float*)(ws + (size_t)71303168);
    float* stats   = (float*)(ws + (size_t)71303168 + 786432);

    k_convx<<<8192, 256, 0, stream>>>(x, xb, stats);
    k_transw<<<dim3(64, 32), 256, 0, stream>>>(Wq, Wk, Wv, Ws, wb);
    k_gemm<<<dim3(16, 32), 512, 0, stream>>>(xb, wb, bq, bk, bv, bs, qkvs, vt);
    k_attn<<<dim3(32, 8, 3), 512, 0, stream>>>(qkvs, xb, vt, we, o_part, lsa);
    k_comb<<<256, 512, 0, stream>>>(o_part, lsa, qkvs, we, out_pre, stats);
    k_final<<<4096, 512, 0, stream>>>(out_pre, stats, gnw, gnb, gnms, out);
}

// Round 8
// 313.426 us; speedup vs baseline: 1.1063x; 1.1063x over previous
//
#include <hip/hip_runtime.h>

// N=4096 nodes, H=8 heads, D=64, C=512. All fp32 in, fp32 out.
// Pipeline: prep(convert x + transpose W + stat zero, fused) ->
// GEMM(qkv+skip, Q pre-scaled by 0.125*log2e, V also written transposed) ->
// split-j(2) max-free flash attn (exp2 path) -> combine(+skip+stats) ->
// GraphNorm+L2.

typedef short s8v __attribute__((ext_vector_type(8)));       // 8 bf16 (A/B frag)
typedef unsigned short u16x8 __attribute__((ext_vector_type(8)));
typedef unsigned short u16x4 __attribute__((ext_vector_type(4)));
typedef float f4 __attribute__((ext_vector_type(4)));        // C/D frag
typedef unsigned short u16;

__device__ __forceinline__ u16 f2bf(float f) {               // RNE
    union { float f; unsigned u; } v; v.f = f;
    unsigned r = v.u + 0x7fffu + ((v.u >> 16) & 1u);
    return (u16)(r >> 16);
}
__device__ __forceinline__ u16 f2bf_hu(float f) {            // round-half-up, 2 ops (P>=0)
    union { float f; unsigned u; } v; v.f = f;
    return (u16)((v.u + 0x8000u) >> 16);
}
__device__ __forceinline__ float bf2f(u16 h) {
    union { unsigned u; float f; } v; v.u = ((unsigned)h) << 16;
    return v.f;
}

#define GLD16(g, l) __builtin_amdgcn_global_load_lds( \
    (const __attribute__((address_space(1))) void*)(g), \
    (__attribute__((address_space(3))) void*)(l), 16, 0, 0)

// ---------- fused prep: blocks [0,8192) convert x -> bf16 (block 0 zeroes
// stats); blocks [8192,10240) transpose+convert W -> wb[n][k] ----------
__global__ __launch_bounds__(256) void k_prep(const float* __restrict__ x,
                                              const float* __restrict__ Wq,
                                              const float* __restrict__ Wk,
                                              const float* __restrict__ Wv,
                                              const float* __restrict__ Ws,
                                              u16* __restrict__ xb,
                                              u16* __restrict__ wb,
                                              float* __restrict__ stats) {
    __shared__ float tile[64][65];
    int b = blockIdx.x;
    int t = threadIdx.x;
    if (b < 8192) {
        if (b == 0) {
            stats[t] = 0.f; stats[256 + t] = 0.f; stats[512 + t] = 0.f; stats[768 + t] = 0.f;
        }
        size_t i = ((size_t)b * 256 + t) * 8;
        float4 a = *(const float4*)(x + i);
        float4 c = *(const float4*)(x + i + 4);
        u16x8 o;
        o[0]=f2bf(a.x); o[1]=f2bf(a.y); o[2]=f2bf(a.z); o[3]=f2bf(a.w);
        o[4]=f2bf(c.x); o[5]=f2bf(c.y); o[6]=f2bf(c.z); o[7]=f2bf(c.w);
        *(u16x8*)(xb + i) = o;
        return;
    }
    int bb = b - 8192;
    int k0 = (bb & 63) * 64;
    int n0 = (bb >> 6) * 64;
    const float* W = (n0 < 512) ? Wq : (n0 < 1024) ? Wk : (n0 < 1536) ? Wv : Ws;
    int col0 = n0 & 511;
#pragma unroll
    for (int q = 0; q < 4; q++) {
        int idx = t + 256 * q;
        int row = idx >> 4, c4 = (idx & 15) * 4;
        float4 v = *(const float4*)&W[(size_t)(k0 + row) * 512 + col0 + c4];
        tile[row][c4 + 0] = v.x; tile[row][c4 + 1] = v.y;
        tile[row][c4 + 2] = v.z; tile[row][c4 + 3] = v.w;
    }
    __syncthreads();
#pragma unroll
    for (int q = 0; q < 2; q++) {
        int idx = t + 256 * q;
        int row = idx >> 3, c8 = (idx & 7) * 8;
        u16x8 o;
#pragma unroll
        for (int j = 0; j < 8; j++) o[j] = f2bf(tile[c8 + j][row]);
        *(u16x8*)&wb[(size_t)(n0 + row) * 4096 + k0 + c8] = o;
    }
}

// ---------- GEMM: qkvs[m][n] = bf16( (sum_k xb[m][k]*wb[n][k] + bias[n]) * scale_seg )
// 128x128 tile, BK=64, XOR-swizzled rows (0 conflicts, verified R5), 8 waves
// (16 waves/CU, verified R6). Q pre-scaled by 0.125*log2e; V also -> vt[d][m].
__global__ __launch_bounds__(512) void k_gemm(const u16* __restrict__ xb,
                                              const u16* __restrict__ wb,
                                              const float* __restrict__ bq,
                                              const float* __restrict__ bk,
                                              const float* __restrict__ bv,
                                              const float* __restrict__ bs,
                                              u16* __restrict__ qkvs,
                                              u16* __restrict__ vt) {
    __shared__ __align__(16) u16 A_lds[128 * 64];
    __shared__ __align__(16) u16 B_lds[128 * 64];
    int tid = threadIdx.x;
    int w = tid >> 6, lane = tid & 63;
    int wr = w >> 1, wc = w & 1;
    int L = lane & 15, q = lane >> 4;
    int m0 = blockIdx.y * 128, n0 = blockIdx.x * 128;

    const f4 fz = {0.f, 0.f, 0.f, 0.f};
    f4 acc[2][4];
#pragma unroll
    for (int r = 0; r < 2; r++)
#pragma unroll
        for (int t = 0; t < 4; t++) acc[r][t] = fz;

    int r8 = lane >> 3;                 // source row within 8-row group
    int csw = ((lane & 7) ^ r8) * 8;    // XOR-swizzled source chunk (u16 units)
    const u16* gS;
    u16* lds_s;
    int rb0;
    if (w < 4) { gS = xb + (size_t)(m0 + r8) * 4096 + csw; lds_s = A_lds; rb0 = 32 * w; }
    else       { gS = wb + (size_t)(n0 + r8) * 4096 + csw; lds_s = B_lds; rb0 = 32 * (w - 4); }

    for (int kt = 0; kt < 64; ++kt) {
        int k0 = kt * 64;
#pragma unroll
        for (int g = 0; g < 4; g++) {
            int rb = rb0 + 8 * g;
            GLD16(gS + (size_t)rb * 4096 + k0, &lds_s[rb * 64]);
        }
        __syncthreads();
        s8v a[2][2], b[4][2];
#pragma unroll
        for (int r = 0; r < 2; r++) {
            int row = wr * 32 + 16 * r + L;
            int r7 = row & 7;
            a[r][0] = *(const s8v*)&A_lds[row * 64 + ((q ^ r7) * 8)];
            a[r][1] = *(const s8v*)&A_lds[row * 64 + (((4 + q) ^ r7) * 8)];
        }
#pragma unroll
        for (int t = 0; t < 4; t++) {
            int row = wc * 64 + 16 * t + L;
            int r7 = row & 7;
            b[t][0] = *(const s8v*)&B_lds[row * 64 + ((q ^ r7) * 8)];
            b[t][1] = *(const s8v*)&B_lds[row * 64 + (((4 + q) ^ r7) * 8)];
        }
#pragma unroll
        for (int r = 0; r < 2; r++)
#pragma unroll
            for (int t = 0; t < 4; t++) {
                acc[r][t] = __builtin_amdgcn_mfma_f32_16x16x32_bf16(a[r][0], b[t][0], acc[r][t], 0, 0, 0);
                acc[r][t] = __builtin_amdgcn_mfma_f32_16x16x32_bf16(a[r][1], b[t][1], acc[r][t], 0, 0, 0);
            }
        __syncthreads();
    }

#pragma unroll
    for (int t = 0; t < 4; t++) {
        int n = n0 + wc * 64 + 16 * t + L;
        int seg = n >> 9, o = n & 511;
        const float* bp = (seg == 0) ? bq : (seg == 1) ? bk : (seg == 2) ? bv : bs;
        float bias = bp[o];
        float scale = (seg == 0) ? 0.1803368801f : 1.f;  // 0.125 * log2(e)
#pragma unroll
        for (int r = 0; r < 2; r++) {
            int mbase = m0 + wr * 32 + 16 * r + 4 * q;
            u16x4 hv;
#pragma unroll
            for (int q2 = 0; q2 < 4; q2++) {
                u16 hb = f2bf((acc[r][t][q2] + bias) * scale);
                hv[q2] = hb;
                qkvs[(size_t)(mbase + q2) * 2048 + n] = hb;
            }
            if (seg == 2)  // fused V transpose: vt[d][m], 4 contiguous m -> 8B store
                *(u16x4*)&vt[(size_t)(n - 1024) * 4096 + mbase] = hv;
        }
    }
}

// ---------- split-j(2) max-free attention (R6-proven geometry) ----------
// block = (i-tile 64, head h, split sp); 4 waves, wave w owns rows 16w..16w+15.
// K/V'/Q staged via GLD16 into unpadded 64x64 tiles with XOR chunk swizzle.
// Q pre-scaled by 0.125*log2e: p = exp2(min(qk' + xx*qe', 115)) -- no running max;
// partials o, l, sa are pure sums.
__global__ __launch_bounds__(256, 4) void k_attn(const u16* __restrict__ qkvs,
                                                 const u16* __restrict__ xb,
                                                 const u16* __restrict__ vt,
                                                 const float* __restrict__ we,
                                                 float* __restrict__ o_part,
                                                 float* __restrict__ lsa_part) {
    __shared__ __align__(16) u16 K_lds[64 * 64];  // swizzled (also Q staging)
    __shared__ __align__(16) u16 V_lds[64 * 64];  // swizzled, rows=d cols=j
    __shared__ __align__(16) u16 P_lds[64 * 72];  // padded, plain layout
    __shared__ __align__(16) u16 X_lds[64 * 72];  // padded bf16 x tile [j][i]
    __shared__ float qe8[64];

    int tid = threadIdx.x;
    int w = tid >> 6, lane = tid & 63;
    int L = lane & 15, q = lane >> 4;
    int i0 = blockIdx.x * 64;
    int h = blockIdx.y, hc = h * 64;
    int sp = blockIdx.z;

    int r8 = lane >> 3;                 // GLD16 source row within 8-row group
    int csw = ((lane & 7) ^ r8) * 8;    // XOR-swizzled source chunk (u16 units)

    // ---- stage Q into K_lds (GLD16, swizzled) ----
    {
        const u16* g0 = qkvs + (size_t)i0 * 2048 + hc;
#pragma unroll
        for (int ih = 0; ih < 2; ih++) {
            int rb = 16 * w + 8 * ih;
            GLD16(g0 + (size_t)(rb + r8) * 2048 + csw, &K_lds[rb * 64]);
        }
    }
    __syncthreads();

    s8v qf[2];
#pragma unroll
    for (int c = 0; c < 2; c++) {
        int row = 16 * w + L;
        qf[c] = *(const s8v*)&K_lds[row * 64 + (((4 * c + q) ^ (row & 7)) * 8)];
    }
    if (tid < 64) {  // qe8[i] = q'_i . we_h   (q' already carries 0.125*log2e)
        float s = 0.f;
        int r7 = tid & 7;
#pragma unroll
        for (int d = 0; d < 64; d++)
            s += bf2f(K_lds[tid * 64 + ((d >> 3) ^ r7) * 8 + (d & 7)]) * we[hc + d];
        qe8[tid] = s;
    }
    __syncthreads();

    float qe_r[4];
#pragma unroll
    for (int r = 0; r < 4; r++) qe_r[r] = qe8[16 * w + 4 * q + r];

    const f4 fz = {0.f, 0.f, 0.f, 0.f};
    f4 o_acc[4];
    float l_p[4], sa_p[4];
#pragma unroll
    for (int r = 0; r < 4; r++) { l_p[r] = 0.f; sa_p[r] = 0.f; }
#pragma unroll
    for (int t = 0; t < 4; t++) o_acc[t] = fz;

    for (int jt64 = 0; jt64 < 32; ++jt64) {
        int j0 = sp * 2048 + jt64 * 64;
        // stage K (GLD16)
        {
            const u16* g0 = qkvs + (size_t)j0 * 2048 + 512 + hc;
#pragma unroll
            for (int ih = 0; ih < 2; ih++) {
                int rb = 16 * w + 8 * ih;
                GLD16(g0 + (size_t)(rb + r8) * 2048 + csw, &K_lds[rb * 64]);
            }
        }
        // stage V^T (GLD16): rows are d, cols j
        {
            const u16* g0 = vt + (size_t)hc * 4096 + j0;
#pragma unroll
            for (int ih = 0; ih < 2; ih++) {
                int rb = 16 * w + 8 * ih;
                GLD16(g0 + (size_t)(rb + r8) * 4096 + csw, &V_lds[rb * 64]);
            }
        }
        // stage X tile bf16: X_lds[j][i] (padded 72, plain)
#pragma unroll
        for (int qq = 0; qq < 2; qq++) {
            int idx = tid + 256 * qq;
            int row = idx >> 3, c8 = (idx & 7) * 8;
            *(s8v*)&X_lds[row * 72 + c8] =
                *(const s8v*)&xb[(size_t)(j0 + row) * 4096 + i0 + c8];
        }
        __syncthreads();

#pragma unroll
        for (int jt = 0; jt < 4; jt++) {
            int n = L + 16 * jt;
            int n7 = n & 7;
            s8v b0 = *(const s8v*)&K_lds[n * 64 + ((q ^ n7) * 8)];
            s8v b1 = *(const s8v*)&K_lds[n * 64 + (((4 + q) ^ n7) * 8)];
            f4 acc = fz;
            acc = __builtin_amdgcn_mfma_f32_16x16x32_bf16(qf[0], b0, acc, 0, 0, 0);
            acc = __builtin_amdgcn_mfma_f32_16x16x32_bf16(qf[1], b1, acc, 0, 0, 0);
            u16x4 xv4 = *(const u16x4*)&X_lds[n * 72 + 16 * w + 4 * q];
#pragma unroll
            for (int r = 0; r < 4; r++) {
                float xx = bf2f(xv4[r]);
                float s = fminf(acc[r] + xx * qe_r[r], 115.f);   // log2 units
                float p = __builtin_amdgcn_exp2f(s);
                l_p[r] += p;
                sa_p[r] += p * xx;
                P_lds[(16 * w + 4 * q + r) * 72 + n] = f2bf_hu(p);
            }
        }

        // PV (wave-local P round-trip; same-wave rows only)
        {
            int row = 16 * w + L;
            s8v a0 = *(const s8v*)&P_lds[row * 72 + q * 8];
            s8v a1 = *(const s8v*)&P_lds[row * 72 + 32 + q * 8];
#pragma unroll
            for (int t = 0; t < 4; t++) {
                int n = L + 16 * t;
                int n7 = n & 7;
                s8v b0 = *(const s8v*)&V_lds[n * 64 + ((q ^ n7) * 8)];
                s8v b1 = *(const s8v*)&V_lds[n * 64 + (((4 + q) ^ n7) * 8)];
                o_acc[t] = __builtin_amdgcn_mfma_f32_16x16x32_bf16(a0, b0, o_acc[t], 0, 0, 0);
                o_acc[t] = __builtin_amdgcn_mfma_f32_16x16x32_bf16(a1, b1, o_acc[t], 0, 0, 0);
            }
        }
        __syncthreads();
    }

    // epilogue: write raw partials (division happens in k_comb after summing l)
#pragma unroll
    for (int r = 0; r < 4; r++) {
        float l = l_p[r], sa = sa_p[r];
        l += __shfl_xor(l, 1);  sa += __shfl_xor(sa, 1);
        l += __shfl_xor(l, 2);  sa += __shfl_xor(sa, 2);
        l += __shfl_xor(l, 4);  sa += __shfl_xor(sa, 4);
        l += __shfl_xor(l, 8);  sa += __shfl_xor(sa, 8);
        int i = i0 + 16 * w + 4 * q + r;
#pragma unroll
        for (int t = 0; t < 4; t++)
            o_part[((size_t)sp * 4096 + i) * 512 + hc + L + 16 * t] = o_acc[t][r];
        if (L == 0) {
            size_t bi = (((size_t)sp * 4096 + i) * 8 + h) * 2;
            lsa_part[bi] = l;
            lsa_part[bi + 1] = sa;
        }
    }
}

// ---------- combine splits + skip + out_pre + column stats ----------
__global__ __launch_bounds__(512) void k_comb(const float* __restrict__ o_part,
                                              const float* __restrict__ lsa,
                                              const u16* __restrict__ qkvs,
                                              const float* __restrict__ we,
                                              float* __restrict__ out_pre,
                                              float* __restrict__ stats) {
    int c = threadIdx.x;
    int r0 = blockIdx.x * 64;
    int h = c >> 6;
    float wec = we[c];
    float s = 0.f, s2 = 0.f;
    for (int ii = 0; ii < 64; ii++) {
        int i = r0 + ii;
        size_t b0 = ((size_t)i * 8 + h) * 2;
        size_t b1 = (((size_t)4096 + i) * 8 + h) * 2;
        float l = lsa[b0] + lsa[b1];
        float sa = lsa[b0 + 1] + lsa[b1 + 1];
        float o = o_part[(size_t)i * 512 + c] + o_part[((size_t)4096 + i) * 512 + c];
        float inv = 1.f / l;
        float v = (o + sa * wec) * inv + bf2f(qkvs[(size_t)i * 2048 + 1536 + c]);
        out_pre[(size_t)i * 512 + c] = v;
        s += v; s2 += v * v;
    }
    atomicAdd(&stats[c], s);
    atomicAdd(&stats[512 + c], s2);
}

// ---------- GraphNorm + per-row L2 normalize ----------
__global__ __launch_bounds__(512) void k_final(const float* __restrict__ out_pre,
                                               const float* __restrict__ stats,
                                               const float* __restrict__ gn_w,
                                               const float* __restrict__ gn_b,
                                               const float* __restrict__ gn_ms,
                                               float* __restrict__ out) {
    __shared__ float red[8];
    int c = threadIdx.x;
    int i = blockIdx.x;
    float mean = stats[c] * (1.f / 4096.f);
    float ex2 = stats[512 + c] * (1.f / 4096.f);
    float g = gn_ms[c];
    float var = ex2 - (2.f * g - g * g) * mean * mean;
    float y = gn_w[c] * (out_pre[(size_t)i * 512 + c] - g * mean) * rsqrtf(var + 1e-5f) + gn_b[c];
    float qv = y * y;
    qv += __shfl_xor(qv, 1);  qv += __shfl_xor(qv, 2);  qv += __shfl_xor(qv, 4);
    qv += __shfl_xor(qv, 8);  qv += __shfl_xor(qv, 16); qv += __shfl_xor(qv, 32);
    if ((c & 63) == 0) red[c >> 6] = qv;
    __syncthreads();
    float tot = 0.f;
#pragma unroll
    for (int k = 0; k < 8; k++) tot += red[k];
    out[(size_t)i * 512 + c] = y * rsqrtf(tot);
}

extern "C" void kernel_launch(void* const* d_in, const int* in_sizes, int n_in,
                              void* d_out, int out_size, void* d_ws, size_t ws_size,
                              hipStream_t stream) {
    (void)in_sizes; (void)n_in; (void)out_size; (void)ws_size;
    const float* x    = (const float*)d_in[0];
    const float* Wq   = (const float*)d_in[1];
    const float* bq   = (const float*)d_in[2];
    const float* Wk   = (const float*)d_in[3];
    const float* bk   = (const float*)d_in[4];
    const float* Wv   = (const float*)d_in[5];
    const float* bv   = (const float*)d_in[6];
    const float* we   = (const float*)d_in[7];
    const float* Ws   = (const float*)d_in[8];
    const float* bs   = (const float*)d_in[9];
    const float* gnw  = (const float*)d_in[10];
    const float* gnb  = (const float*)d_in[11];
    const float* gnms = (const float*)d_in[12];
    float* out = (float*)d_out;

    char* ws = (char*)d_ws;
    // Region reuse (all launches sequential on `stream`):
    //   [0,32M):   xb (prep..attn) then out_pre overlays (comb..final)
    //   [32M,48M): wb (prep..gemm) then o_part fp32 2x8MB overlays (attn..comb)
    //   [48M,64M): qkvs (gemm..comb)
    //   [64M,68M): vt (gemm..attn)
    //   [68M,..):  lsa_part (512KB) ; stats (4KB)
    u16* xb        = (u16*)(ws);
    float* out_pre = (float*)(ws);
    u16* wb        = (u16*)(ws + (size_t)33554432);
    float* o_part  = (float*)(ws + (size_t)33554432);
    u16* qkvs      = (u16*)(ws + (size_t)50331648);
    u16* vt        = (u16*)(ws + (size_t)67108864);
    float* lsa     = (float*)(ws + (size_t)71303168);
    float* stats   = (float*)(ws + (size_t)71303168 + 524288);

    k_prep<<<10240, 256, 0, stream>>>(x, Wq, Wk, Wv, Ws, xb, wb, stats);
    k_gemm<<<dim3(16, 32), 512, 0, stream>>>(xb, wb, bq, bk, bv, bs, qkvs, vt);
    k_attn<<<dim3(64, 8, 2), 256, 0, stream>>>(qkvs, xb, vt, we, o_part, lsa);
    k_comb<<<64, 512, 0, stream>>>(o_part, lsa, qkvs, we, out_pre, stats);
    k_final<<<4096, 512, 0, stream>>>(out_pre, stats, gnw, gnb, gnms, out);
}

// Round 9
// 312.645 us; speedup vs baseline: 1.1090x; 1.0025x over previous
//
#include <hip/hip_runtime.h>

// N=4096 nodes, H=8 heads, D=64, C=512. All fp32 in, fp32 out.
// Pipeline: prep(convert x + transpose W + stat zero, fused) ->
// GEMM(qkv+skip, Q pre-scaled by 0.125*log2e, V also written transposed) ->
// split-j(2) max-free flash attn (128 i-rows, 8 waves, exp2, fp32 partials) ->
// combine(+skip+stats) -> GraphNorm+L2.

typedef short s8v __attribute__((ext_vector_type(8)));       // 8 bf16 (A/B frag)
typedef unsigned short u16x8 __attribute__((ext_vector_type(8)));
typedef unsigned short u16x4 __attribute__((ext_vector_type(4)));
typedef float f4 __attribute__((ext_vector_type(4)));        // C/D frag
typedef unsigned short u16;

__device__ __forceinline__ u16 f2bf(float f) {               // RNE
    union { float f; unsigned u; } v; v.f = f;
    unsigned r = v.u + 0x7fffu + ((v.u >> 16) & 1u);
    return (u16)(r >> 16);
}
__device__ __forceinline__ u16 f2bf_hu(float f) {            // round-half-up, 2 ops (P>=0)
    union { float f; unsigned u; } v; v.f = f;
    return (u16)((v.u + 0x8000u) >> 16);
}
__device__ __forceinline__ float bf2f(u16 h) {
    union { unsigned u; float f; } v; v.u = ((unsigned)h) << 16;
    return v.f;
}

#define GLD16(g, l) __builtin_amdgcn_global_load_lds( \
    (const __attribute__((address_space(1))) void*)(g), \
    (__attribute__((address_space(3))) void*)(l), 16, 0, 0)

// ---------- fused prep: blocks [0,8192) convert x -> bf16 (block 0 zeroes
// stats); blocks [8192,10240) transpose+convert W -> wb[n][k] ----------
__global__ __launch_bounds__(256) void k_prep(const float* __restrict__ x,
                                              const float* __restrict__ Wq,
                                              const float* __restrict__ Wk,
                                              const float* __restrict__ Wv,
                                              const float* __restrict__ Ws,
                                              u16* __restrict__ xb,
                                              u16* __restrict__ wb,
                                              float* __restrict__ stats) {
    __shared__ float tile[64][65];
    int b = blockIdx.x;
    int t = threadIdx.x;
    if (b < 8192) {
        if (b == 0) {
            stats[t] = 0.f; stats[256 + t] = 0.f; stats[512 + t] = 0.f; stats[768 + t] = 0.f;
        }
        size_t i = ((size_t)b * 256 + t) * 8;
        float4 a = *(const float4*)(x + i);
        float4 c = *(const float4*)(x + i + 4);
        u16x8 o;
        o[0]=f2bf(a.x); o[1]=f2bf(a.y); o[2]=f2bf(a.z); o[3]=f2bf(a.w);
        o[4]=f2bf(c.x); o[5]=f2bf(c.y); o[6]=f2bf(c.z); o[7]=f2bf(c.w);
        *(u16x8*)(xb + i) = o;
        return;
    }
    int bb = b - 8192;
    int k0 = (bb & 63) * 64;
    int n0 = (bb >> 6) * 64;
    const float* W = (n0 < 512) ? Wq : (n0 < 1024) ? Wk : (n0 < 1536) ? Wv : Ws;
    int col0 = n0 & 511;
#pragma unroll
    for (int q = 0; q < 4; q++) {
        int idx = t + 256 * q;
        int row = idx >> 4, c4 = (idx & 15) * 4;
        float4 v = *(const float4*)&W[(size_t)(k0 + row) * 512 + col0 + c4];
        tile[row][c4 + 0] = v.x; tile[row][c4 + 1] = v.y;
        tile[row][c4 + 2] = v.z; tile[row][c4 + 3] = v.w;
    }
    __syncthreads();
#pragma unroll
    for (int q = 0; q < 2; q++) {
        int idx = t + 256 * q;
        int row = idx >> 3, c8 = (idx & 7) * 8;
        u16x8 o;
#pragma unroll
        for (int j = 0; j < 8; j++) o[j] = f2bf(tile[c8 + j][row]);
        *(u16x8*)&wb[(size_t)(n0 + row) * 4096 + k0 + c8] = o;
    }
}

// ---------- GEMM: qkvs[m][n] = bf16( (sum_k xb[m][k]*wb[n][k] + bias[n]) * scale_seg )
// 128x128 tile, BK=64, XOR-swizzled rows (0 conflicts, verified R5), 8 waves
// (16 waves/CU, verified R6). Q pre-scaled by 0.125*log2e; V also -> vt[d][m].
__global__ __launch_bounds__(512) void k_gemm(const u16* __restrict__ xb,
                                              const u16* __restrict__ wb,
                                              const float* __restrict__ bq,
                                              const float* __restrict__ bk,
                                              const float* __restrict__ bv,
                                              const float* __restrict__ bs,
                                              u16* __restrict__ qkvs,
                                              u16* __restrict__ vt) {
    __shared__ __align__(16) u16 A_lds[128 * 64];
    __shared__ __align__(16) u16 B_lds[128 * 64];
    int tid = threadIdx.x;
    int w = tid >> 6, lane = tid & 63;
    int wr = w >> 1, wc = w & 1;
    int L = lane & 15, q = lane >> 4;
    int m0 = blockIdx.y * 128, n0 = blockIdx.x * 128;

    const f4 fz = {0.f, 0.f, 0.f, 0.f};
    f4 acc[2][4];
#pragma unroll
    for (int r = 0; r < 2; r++)
#pragma unroll
        for (int t = 0; t < 4; t++) acc[r][t] = fz;

    int r8 = lane >> 3;                 // source row within 8-row group
    int csw = ((lane & 7) ^ r8) * 8;    // XOR-swizzled source chunk (u16 units)
    const u16* gS;
    u16* lds_s;
    int rb0;
    if (w < 4) { gS = xb + (size_t)(m0 + r8) * 4096 + csw; lds_s = A_lds; rb0 = 32 * w; }
    else       { gS = wb + (size_t)(n0 + r8) * 4096 + csw; lds_s = B_lds; rb0 = 32 * (w - 4); }

    for (int kt = 0; kt < 64; ++kt) {
        int k0 = kt * 64;
#pragma unroll
        for (int g = 0; g < 4; g++) {
            int rb = rb0 + 8 * g;
            GLD16(gS + (size_t)rb * 4096 + k0, &lds_s[rb * 64]);
        }
        __syncthreads();
        s8v a[2][2], b[4][2];
#pragma unroll
        for (int r = 0; r < 2; r++) {
            int row = wr * 32 + 16 * r + L;
            int r7 = row & 7;
            a[r][0] = *(const s8v*)&A_lds[row * 64 + ((q ^ r7) * 8)];
            a[r][1] = *(const s8v*)&A_lds[row * 64 + (((4 + q) ^ r7) * 8)];
        }
#pragma unroll
        for (int t = 0; t < 4; t++) {
            int row = wc * 64 + 16 * t + L;
            int r7 = row & 7;
            b[t][0] = *(const s8v*)&B_lds[row * 64 + ((q ^ r7) * 8)];
            b[t][1] = *(const s8v*)&B_lds[row * 64 + (((4 + q) ^ r7) * 8)];
        }
#pragma unroll
        for (int r = 0; r < 2; r++)
#pragma unroll
            for (int t = 0; t < 4; t++) {
                acc[r][t] = __builtin_amdgcn_mfma_f32_16x16x32_bf16(a[r][0], b[t][0], acc[r][t], 0, 0, 0);
                acc[r][t] = __builtin_amdgcn_mfma_f32_16x16x32_bf16(a[r][1], b[t][1], acc[r][t], 0, 0, 0);
            }
        __syncthreads();
    }

#pragma unroll
    for (int t = 0; t < 4; t++) {
        int n = n0 + wc * 64 + 16 * t + L;
        int seg = n >> 9, o = n & 511;
        const float* bp = (seg == 0) ? bq : (seg == 1) ? bk : (seg == 2) ? bv : bs;
        float bias = bp[o];
        float scale = (seg == 0) ? 0.1803368801f : 1.f;  // 0.125 * log2(e)
#pragma unroll
        for (int r = 0; r < 2; r++) {
            int mbase = m0 + wr * 32 + 16 * r + 4 * q;
            u16x4 hv;
#pragma unroll
            for (int q2 = 0; q2 < 4; q2++) {
                u16 hb = f2bf((acc[r][t][q2] + bias) * scale);
                hv[q2] = hb;
                qkvs[(size_t)(mbase + q2) * 2048 + n] = hb;
            }
            if (seg == 2)  // fused V transpose: vt[d][m], 4 contiguous m -> 8B store
                *(u16x4*)&vt[(size_t)(n - 1024) * 4096 + mbase] = hv;
        }
    }
}

// ---------- split-j(2) max-free attention, 128 i-rows x 8 waves per block ----------
// R7 geometry with the poison removed: o_part stays fp32 (R7's bf16 scalar
// stores caused 3.75x write amplification + XCD L2 thrash -> FETCH x3).
// Wave w owns i-rows 16w..16w+15. K/V'/Q staged via GLD16 into unpadded
// stride-64 tiles with XOR chunk swizzle (conflict-free b128 reads, verified).
// p = exp2(min(qk' + xx*qe', 115)); partials o, l, sa are pure sums.
__global__ __launch_bounds__(512, 4) void k_attn(const u16* __restrict__ qkvs,
                                                 const u16* __restrict__ xb,
                                                 const u16* __restrict__ vt,
                                                 const float* __restrict__ we,
                                                 float* __restrict__ o_part,
                                                 float* __restrict__ lsa_part) {
    __shared__ __align__(16) u16 K_lds[64 * 64];    // swizzled [j][d]
    __shared__ __align__(16) u16 V_lds[64 * 64];    // swizzled [d][j]
    __shared__ __align__(16) u16 P_lds[128 * 72];   // padded (also Q staging, stride 64)
    __shared__ __align__(16) u16 X_lds[64 * 136];   // padded bf16 x tile [j][i]
    __shared__ float qe_s[128];

    int tid = threadIdx.x;
    int w = tid >> 6, lane = tid & 63;
    int L = lane & 15, q = lane >> 4;
    int i0 = blockIdx.x * 128;
    int h = blockIdx.y, hc = h * 64;
    int sp = blockIdx.z;

    int r8 = lane >> 3;                 // GLD16 source row within 8-row group
    int csw = ((lane & 7) ^ r8) * 8;    // XOR-swizzled source chunk (u16 units)

    // ---- stage Q (128 rows) into P_lds (stride 64, swizzled) ----
    {
        const u16* g0 = qkvs + (size_t)i0 * 2048 + hc;
#pragma unroll
        for (int ih = 0; ih < 2; ih++) {
            int rb = 16 * w + 8 * ih;
            GLD16(g0 + (size_t)(rb + r8) * 2048 + csw, &P_lds[rb * 64]);
        }
    }
    __syncthreads();

    s8v qf[2];
#pragma unroll
    for (int c = 0; c < 2; c++) {
        int row = 16 * w + L;
        qf[c] = *(const s8v*)&P_lds[row * 64 + (((4 * c + q) ^ (row & 7)) * 8)];
    }
    if (tid < 128) {  // qe[i] = q'_i . we_h  (q' already carries 0.125*log2e)
        float s = 0.f;
        int r7 = tid & 7;
#pragma unroll
        for (int d = 0; d < 64; d++)
            s += bf2f(P_lds[tid * 64 + ((d >> 3) ^ r7) * 8 + (d & 7)]) * we[hc + d];
        qe_s[tid] = s;
    }
    __syncthreads();

    float qe_r[4];
#pragma unroll
    for (int r = 0; r < 4; r++) qe_r[r] = qe_s[16 * w + 4 * q + r];

    const f4 fz = {0.f, 0.f, 0.f, 0.f};
    f4 o_acc[4];
    float l_p[4], sa_p[4];
#pragma unroll
    for (int r = 0; r < 4; r++) { l_p[r] = 0.f; sa_p[r] = 0.f; }
#pragma unroll
    for (int t = 0; t < 4; t++) o_acc[t] = fz;

    for (int jt64 = 0; jt64 < 32; ++jt64) {
        int j0 = sp * 2048 + jt64 * 64;
        // stage K: wave w stages rows 8w..8w+7 (one GLD16 per wave)
        GLD16(qkvs + (size_t)(j0 + 8 * w + r8) * 2048 + 512 + hc + csw, &K_lds[8 * w * 64]);
        // stage V^T: rows are d
        GLD16(vt + (size_t)(hc + 8 * w + r8) * 4096 + j0 + csw, &V_lds[8 * w * 64]);
        // stage X tile bf16: X_lds[j][i], 64 x 128, stride 136
#pragma unroll
        for (int qq = 0; qq < 2; qq++) {
            int idx = tid + 512 * qq;
            int row = idx >> 4, c8 = (idx & 15) * 8;
            *(s8v*)&X_lds[row * 136 + c8] =
                *(const s8v*)&xb[(size_t)(j0 + row) * 4096 + i0 + c8];
        }
        __syncthreads();

#pragma unroll
        for (int jt = 0; jt < 4; jt++) {
            int n = L + 16 * jt;
            int n7 = n & 7;
            s8v b0 = *(const s8v*)&K_lds[n * 64 + ((q ^ n7) * 8)];
            s8v b1 = *(const s8v*)&K_lds[n * 64 + (((4 + q) ^ n7) * 8)];
            f4 acc = fz;
            acc = __builtin_amdgcn_mfma_f32_16x16x32_bf16(qf[0], b0, acc, 0, 0, 0);
            acc = __builtin_amdgcn_mfma_f32_16x16x32_bf16(qf[1], b1, acc, 0, 0, 0);
            u16x4 xv4 = *(const u16x4*)&X_lds[n * 136 + 16 * w + 4 * q];
#pragma unroll
            for (int r = 0; r < 4; r++) {
                float xx = bf2f(xv4[r]);
                float s = fminf(acc[r] + xx * qe_r[r], 115.f);   // log2 units
                float p = __builtin_amdgcn_exp2f(s);
                l_p[r] += p;
                sa_p[r] += p * xx;
                P_lds[(16 * w + 4 * q + r) * 72 + n] = f2bf_hu(p);
            }
        }

        // PV (wave-local P round-trip; same-wave rows only)
        {
            int row = 16 * w + L;
            s8v a0 = *(const s8v*)&P_lds[row * 72 + q * 8];
            s8v a1 = *(const s8v*)&P_lds[row * 72 + 32 + q * 8];
#pragma unroll
            for (int t = 0; t < 4; t++) {
                int n = L + 16 * t;
                int n7 = n & 7;
                s8v b0 = *(const s8v*)&V_lds[n * 64 + ((q ^ n7) * 8)];
                s8v b1 = *(const s8v*)&V_lds[n * 64 + (((4 + q) ^ n7) * 8)];
                o_acc[t] = __builtin_amdgcn_mfma_f32_16x16x32_bf16(a0, b0, o_acc[t], 0, 0, 0);
                o_acc[t] = __builtin_amdgcn_mfma_f32_16x16x32_bf16(a1, b1, o_acc[t], 0, 0, 0);
            }
        }
        __syncthreads();
    }

    // epilogue: write raw fp32 partials (division happens in k_comb)
#pragma unroll
    for (int r = 0; r < 4; r++) {
        float l = l_p[r], sa = sa_p[r];
        l += __shfl_xor(l, 1);  sa += __shfl_xor(sa, 1);
        l += __shfl_xor(l, 2);  sa += __shfl_xor(sa, 2);
        l += __shfl_xor(l, 4);  sa += __shfl_xor(sa, 4);
        l += __shfl_xor(l, 8);  sa += __shfl_xor(sa, 8);
        int i = i0 + 16 * w + 4 * q + r;
#pragma unroll
        for (int t = 0; t < 4; t++)
            o_part[((size_t)sp * 4096 + i) * 512 + hc + L + 16 * t] = o_acc[t][r];
        if (L == 0) {
            size_t bi = (((size_t)sp * 4096 + i) * 8 + h) * 2;
            lsa_part[bi] = l;
            lsa_part[bi + 1] = sa;
        }
    }
}

// ---------- combine splits + skip + out_pre + column stats ----------
__global__ __launch_bounds__(512) void k_comb(const float* __restrict__ o_part,
                                              const float* __restrict__ lsa,
                                              const u16* __restrict__ qkvs,
                                              const float* __restrict__ we,
                                              float* __restrict__ out_pre,
                                              float* __restrict__ stats) {
    int c = threadIdx.x;
    int r0 = blockIdx.x * 64;
    int h = c >> 6;
    float wec = we[c];
    float s = 0.f, s2 = 0.f;
    for (int ii = 0; ii < 64; ii++) {
        int i = r0 + ii;
        size_t b0 = ((size_t)i * 8 + h) * 2;
        size_t b1 = (((size_t)4096 + i) * 8 + h) * 2;
        float l = lsa[b0] + lsa[b1];
        float sa = lsa[b0 + 1] + lsa[b1 + 1];
        float o = o_part[(size_t)i * 512 + c] + o_part[((size_t)4096 + i) * 512 + c];
        float inv = 1.f / l;
        float v = (o + sa * wec) * inv + bf2f(qkvs[(size_t)i * 2048 + 1536 + c]);
        out_pre[(size_t)i * 512 + c] = v;
        s += v; s2 += v * v;
    }
    atomicAdd(&stats[c], s);
    atomicAdd(&stats[512 + c], s2);
}

// ---------- GraphNorm + per-row L2 normalize ----------
__global__ __launch_bounds__(512) void k_final(const float* __restrict__ out_pre,
                                               const float* __restrict__ stats,
                                               const float* __restrict__ gn_w,
                                               const float* __restrict__ gn_b,
                                               const float* __restrict__ gn_ms,
                                               float* __restrict__ out) {
    __shared__ float red[8];
    int c = threadIdx.x;
    int i = blockIdx.x;
    float mean = stats[c] * (1.f / 4096.f);
    float ex2 = stats[512 + c] * (1.f / 4096.f);
    float g = gn_ms[c];
    float var = ex2 - (2.f * g - g * g) * mean * mean;
    float y = gn_w[c] * (out_pre[(size_t)i * 512 + c] - g * mean) * rsqrtf(var + 1e-5f) + gn_b[c];
    float qv = y * y;
    qv += __shfl_xor(qv, 1);  qv += __shfl_xor(qv, 2);  qv += __shfl_xor(qv, 4);
    qv += __shfl_xor(qv, 8);  qv += __shfl_xor(qv, 16); qv += __shfl_xor(qv, 32);
    if ((c & 63) == 0) red[c >> 6] = qv;
    __syncthreads();
    float tot = 0.f;
#pragma unroll
    for (int k = 0; k < 8; k++) tot += red[k];
    out[(size_t)i * 512 + c] = y * rsqrtf(tot);
}

extern "C" void kernel_launch(void* const* d_in, const int* in_sizes, int n_in,
                              void* d_out, int out_size, void* d_ws, size_t ws_size,
                              hipStream_t stream) {
    (void)in_sizes; (void)n_in; (void)out_size; (void)ws_size;
    const float* x    = (const float*)d_in[0];
    const float* Wq   = (const float*)d_in[1];
    const float* bq   = (const float*)d_in[2];
    const float* Wk   = (const float*)d_in[3];
    const float* bk   = (const float*)d_in[4];
    const float* Wv   = (const float*)d_in[5];
    const float* bv   = (const float*)d_in[6];
    const float* we   = (const float*)d_in[7];
    const float* Ws   = (const float*)d_in[8];
    const float* bs   = (const float*)d_in[9];
    const float* gnw  = (const float*)d_in[10];
    const float* gnb  = (const float*)d_in[11];
    const float* gnms = (const float*)d_in[12];
    float* out = (float*)d_out;

    char* ws = (char*)d_ws;
    // Region reuse (all launches sequential on `stream`):
    //   [0,32M):   xb (prep..attn) then out_pre overlays (comb..final)
    //   [32M,48M): wb (prep..gemm) then o_part fp32 2x8MB overlays (attn..comb)
    //   [48M,64M): qkvs (gemm..comb)
    //   [64M,68M): vt (gemm..attn)
    //   [68M,..):  lsa_part (512KB) ; stats (4KB)
    u16* xb        = (u16*)(ws);
    float* out_pre = (float*)(ws);
    u16* wb        = (u16*)(ws + (size_t)33554432);
    float* o_part  = (float*)(ws + (size_t)33554432);
    u16* qkvs      = (u16*)(ws + (size_t)50331648);
    u16* vt        = (u16*)(ws + (size_t)67108864);
    float* lsa     = (float*)(ws + (size_t)71303168);
    float* stats   = (float*)(ws + (size_t)71303168 + 524288);

    k_prep<<<10240, 256, 0, stream>>>(x, Wq, Wk, Wv, Ws, xb, wb, stats);
    k_gemm<<<dim3(16, 32), 512, 0, stream>>>(xb, wb, bq, bk, bv, bs, qkvs, vt);
    k_attn<<<dim3(32, 8, 2), 512, 0, stream>>>(qkvs, xb, vt, we, o_part, lsa);
    k_comb<<<64, 512, 0, stream>>>(o_part, lsa, qkvs, we, out_pre, stats);
    k_final<<<4096, 512, 0, stream>>>(out_pre, stats, gnw, gnb, gnms, out);
}